// Round 5
// baseline (255.274 us; speedup 1.0000x reference)
//
#include <hip/hip_runtime.h>

// crossCorrelation3D: local (9x9x9) NCC loss, fused single kernel.
// B=2, C=1, D=H=W=160, fp32. Output = -mean(cc), scalar.
//
// R5 = R2's proven skeleton (119us dispatch) with exactly three deltas:
//   1. DCHUNK 32->16: grid 2000 blocks (R2's 1000 was grid-limited at 41%
//      occupancy). +20% plane work, betting residency gain dominates.
//   2. tmp5 field stride 385 (=1 mod 32): step3's same-(r,w)-diff-f lanes
//      were 4-way bank-conflicted at stride 384 (=0 mod 32); now <=2-way
//      (free per m136). Step2 stores stay stride-1 across lanes.
//   3. Fused finalize via atomic counter (validated R3/R4): one kernel node.
// Everything else (3 barriers/plane, 80-lane sliding step3, skip-invalid
// boundary planes, no prefetch) is IDENTICAL to R2 — R3/R4 showed the
// "improvements" on top of this skeleton were collectively negative.

constexpr int NB = 2, ND = 160, NH = 160, NW = 160;
constexpr int TH = 16, TW = 16;
constexpr int DCHUNK = 16;
constexpr int NDCH = ND / DCHUNK;          // 10
constexpr int NBLOCKS = (NW / TW) * (NH / TH) * NB * NDCH;  // 2000
constexpr float INV_K = 1.0f / 729.0f;
constexpr double INV_COUNT = 1.0 / (double(NB) * ND * NH * NW);
constexpr int T5S = 385;                   // tmp5 per-field stride (+1 pad)

__device__ __forceinline__ void compute_plane(
    const float* __restrict__ in, const float* __restrict__ tg,
    int b, int dp, int h0, int w0, int tid,
    float* __restrict__ inT, float* __restrict__ tgT,
    float* __restrict__ tmp5, float* __restrict__ Pbuf)
{
    // ---- step 1: load 24x24 halo plane (float4 rows); transform target
    // t=(raw+1)/2 at load so zero padding contributes t=0. Each 4-wide
    // segment is entirely in- or out-of-bounds (w0%16==0, halo=4).
    if (tid < 144) {
        int r = tid / 6;
        int q = tid - r * 6;
        int gh = h0 - 4 + r;
        int gw = w0 - 4 + q * 4;
        float4 iv = make_float4(0.f, 0.f, 0.f, 0.f);
        float4 tv = make_float4(0.f, 0.f, 0.f, 0.f);
        if (((unsigned)gh < (unsigned)NH) && ((unsigned)gw < (unsigned)NW)) {
            long base = ((long)((b * ND + dp) * NH + gh)) * NW + gw;
            iv = *reinterpret_cast<const float4*>(in + base);
            float4 rv = *reinterpret_cast<const float4*>(tg + base);
            tv.x = fmaf(rv.x, 0.5f, 0.5f);
            tv.y = fmaf(rv.y, 0.5f, 0.5f);
            tv.z = fmaf(rv.z, 0.5f, 0.5f);
            tv.w = fmaf(rv.w, 0.5f, 0.5f);
        }
        reinterpret_cast<float4*>(inT)[r * 6 + q] = iv;
        reinterpret_cast<float4*>(tgT)[r * 6 + q] = tv;
    }
    __syncthreads();

    // ---- step 2: w-direction 9-sums of 5 product fields -> tmp5 ----
    {
        int pos = tid;
        #pragma unroll
        for (int rep = 0; rep < 2; ++rep) {
            if (pos < 384) {
                int r = pos >> 4, wo = pos & 15;
                const float* ir = inT + r * 24 + wo;
                const float* tr = tgT + r * 24 + wo;
                float s0 = 0.f, s1 = 0.f, s2 = 0.f, s3 = 0.f, s4 = 0.f;
                #pragma unroll
                for (int k = 0; k < 9; ++k) {
                    float ivv = ir[k];
                    float t = tr[k];            // already transformed (pad=0)
                    s0 += t;
                    s1 += ivv;
                    s2 = fmaf(t, t, s2);
                    s3 = fmaf(ivv, ivv, s3);
                    s4 = fmaf(ivv, t, s4);
                }
                int o = r * 16 + wo;
                tmp5[0 * T5S + o] = s0;
                tmp5[1 * T5S + o] = s1;
                tmp5[2 * T5S + o] = s2;
                tmp5[3 * T5S + o] = s3;
                tmp5[4 * T5S + o] = s4;
            }
            pos += 256;
        }
    }
    __syncthreads();

    // ---- step 3: h-direction sliding 9-sums -> Pbuf[5][16][16] ----
    if (tid < 80) {
        int f = tid >> 4, w = tid & 15;
        const float* basep = tmp5 + f * T5S + w;
        float s = 0.f;
        #pragma unroll
        for (int r = 0; r < 8; ++r) s += basep[r * 16];
        #pragma unroll
        for (int ho = 0; ho < 16; ++ho) {
            s += basep[(ho + 8) * 16];
            Pbuf[f * 256 + ho * 16 + w] = s;
            s -= basep[ho * 16];
        }
    }
    __syncthreads();
}

__global__ void __launch_bounds__(256)
cc3d_main(const float* __restrict__ in, const float* __restrict__ tg,
          const float* __restrict__ fl, float* __restrict__ out,
          double* __restrict__ acc_ws, unsigned* __restrict__ cnt_ws)
{
    __shared__ float inT[24 * 24];
    __shared__ float tgT[24 * 24];
    __shared__ float tmp5[5 * T5S];
    __shared__ float Pbuf[5 * 256];
    __shared__ float red[4];

    const int tid = threadIdx.x;
    const int w0 = blockIdx.x * TW;
    const int h0 = blockIdx.y * TH;
    const int bz = blockIdx.z;
    const int b  = bz / NDCH;
    const int d0 = (bz - b * NDCH) * DCHUNK;

    // D-direction ring of 9 plane values per field, statically indexed.
    float ring[45];
    #pragma unroll
    for (int i = 0; i < 45; ++i) ring[i] = 0.f;
    float S[5] = {0.f, 0.f, 0.f, 0.f, 0.f};
    float acc = 0.f;

    // ---- prefill planes d0-4 .. d0+3 into ring slots 0..7 ----
    #pragma unroll
    for (int l = 0; l < 8; ++l) {
        int dp = d0 - 4 + l;          // upper bound can't fail in prefill
        bool valid = (dp >= 0);       // block-uniform
        if (valid) compute_plane(in, tg, b, dp, h0, w0, tid, inT, tgT, tmp5, Pbuf);
        #pragma unroll
        for (int f = 0; f < 5; ++f) {
            float pv = valid ? Pbuf[f * 256 + tid] : 0.f;
            ring[f * 9 + l] = pv;
            S[f] += pv;
        }
    }

    // ---- main march over outputs d0 .. d0+DCHUNK-1 ----
    for (int jbase = 0; jbase < DCHUNK; jbase += 9) {
        #pragma unroll
        for (int jj = 0; jj < 9; ++jj) {
            int j = jbase + jj;
            if (j < DCHUNK) {         // block-uniform guard
                int dout = d0 + j;
                int dp = dout + 4;
                bool valid = (dp < ND);  // block-uniform
                if (valid) compute_plane(in, tg, b, dp, h0, w0, tid, inT, tgT, tmp5, Pbuf);
                const int slot = (jj + 8) % 9;   // compile-time (jbase % 9 == 0)
                #pragma unroll
                for (int f = 0; f < 5; ++f) {
                    float pn = valid ? Pbuf[f * 256 + tid] : 0.f;
                    S[f] += pn - ring[f * 9 + slot];
                    ring[f * 9 + slot] = pn;
                }
                int hh = tid >> 4, ww = tid & 15;
                long fidx = ((long)((b * ND + dout) * NH + (h0 + hh))) * NW + (w0 + ww);
                float x = fl[fidx];
                float wgt = 1.0f / (1.0f + __expf(-x));   // sigmoid, GAMMA=1
                float Ts = S[0], Is = S[1], TTs = S[2], IIs = S[3], ITs = S[4];
                float Ihat = Is * INV_K;
                float That = Ts * INV_K;
                float cross = ITs - Ihat * Ts - That * Is + That * Ihat * 729.0f;
                float T_var = TTs - 2.0f * That * Ts + That * That * 729.0f;
                float I_var = IIs - 2.0f * Ihat * Is + Ihat * Ihat * 729.0f;
                float cc = cross * cross * wgt / (T_var * I_var + 1e-5f);
                acc += cc;
            }
        }
    }

    // ---- block reduction -> device atomic; last block finalizes ----
    #pragma unroll
    for (int off = 32; off > 0; off >>= 1) acc += __shfl_down(acc, off);
    if ((tid & 63) == 0) red[tid >> 6] = acc;
    __syncthreads();
    if (tid == 0) {
        const double v = (double)red[0] + (double)red[1] + (double)red[2] + (double)red[3];
        atomicAdd(acc_ws, v);
        __threadfence();
        const unsigned done = atomicAdd(cnt_ws, 1u);
        if (done == (unsigned)(NBLOCKS - 1)) {
            __threadfence();
            const double a = atomicAdd(acc_ws, 0.0);   // coherent read
            out[0] = (float)(-(a * INV_COUNT));
        }
    }
}

extern "C" void kernel_launch(void* const* d_in, const int* in_sizes, int n_in,
                              void* d_out, int out_size, void* d_ws, size_t ws_size,
                              hipStream_t stream)
{
    const float* in = (const float*)d_in[0];   // 'input'
    const float* tg = (const float*)d_in[1];   // 'target'
    const float* fl = (const float*)d_in[2];   // 'flow'
    float* out = (float*)d_out;
    double* acc = (double*)d_ws;
    unsigned* cnt = (unsigned*)((char*)d_ws + 8);

    hipMemsetAsync(d_ws, 0, 16, stream);  // zero acc + counter (graph-safe)

    dim3 grid(NW / TW, NH / TH, NB * NDCH);  // (10, 10, 20) = 2000 blocks
    cc3d_main<<<grid, dim3(256), 0, stream>>>(in, tg, fl, out, acc, cnt);
}

// Round 6
// 239.693 us; speedup vs baseline: 1.0650x; 1.0650x over previous
//
#include <hip/hip_runtime.h>

// crossCorrelation3D: local (9x9x9) NCC loss, fused single kernel.
// B=2, C=1, D=H=W=160, fp32. Output = -mean(cc), scalar.
//
// R6 model: the per-CU LDS pipe is the bottleneck (~1640 cyc/plane of LDS
// instructions in the R2 skeleton vs 1830 measured; occupancy/VALU/HBM all
// low because blocks just queue on the LDS pipe — which is why every
// "more blocks" round regressed in proportion to total plane count).
// So: R2 skeleton (DCHUNK=32, grid 1000 = minimal total planes, 3 barriers,
// skip-invalid boundary planes, no prefetch) with LDS traffic cut ~1.6x:
//   step2: sliding-window over w, 96 threads (24 rows x 4 quads): 6 x
//     ds_read_b128 + 5 x ds_write_b128 per thread (was 27 b32 reads +
//     7.5 b32 writes per thread over 256 threads).
//   step3: 80 threads read the 24-value column ONCE into registers (24 b32,
//     was 40) and slide in VGPRs.
//   tmp5 field stride 392 floats (=98 float4, banks 2-way max);
//   Pbuf field stride 264 floats (breaks 4-way write aliasing).

constexpr int NB = 2, ND = 160, NH = 160, NW = 160;
constexpr int TH = 16, TW = 16;
constexpr int DCHUNK = 32;
constexpr int NDCH = ND / DCHUNK;          // 5
constexpr int NBLOCKS = (NW / TW) * (NH / TH) * NB * NDCH;  // 1000
constexpr float INV_K = 1.0f / 729.0f;
constexpr double INV_COUNT = 1.0 / (double(NB) * ND * NH * NW);
constexpr int T5S  = 392;                  // tmp5 field stride (floats)
constexpr int T5S4 = T5S / 4;              // 98 (float4 units)
constexpr int PBS  = 264;                  // Pbuf field stride (floats)

__device__ __forceinline__ void compute_plane(
    const float* __restrict__ in, const float* __restrict__ tg,
    int b, int dp, int h0, int w0, int tid,
    float* __restrict__ inT, float* __restrict__ tgT,
    float* __restrict__ tmp5, float* __restrict__ Pbuf)
{
    // ---- step 1: load 24x24 halo plane (float4 rows); transform target
    // t=(raw+1)/2 at load so zero padding contributes t=0. Each 4-wide
    // segment is entirely in- or out-of-bounds (w0%16==0, halo=4).
    if (tid < 144) {
        int r = tid / 6;
        int q = tid - r * 6;
        int gh = h0 - 4 + r;
        int gw = w0 - 4 + q * 4;
        float4 iv = make_float4(0.f, 0.f, 0.f, 0.f);
        float4 tv = make_float4(0.f, 0.f, 0.f, 0.f);
        if (((unsigned)gh < (unsigned)NH) && ((unsigned)gw < (unsigned)NW)) {
            long base = ((long)((b * ND + dp) * NH + gh)) * NW + gw;
            iv = *reinterpret_cast<const float4*>(in + base);
            float4 rv = *reinterpret_cast<const float4*>(tg + base);
            tv.x = fmaf(rv.x, 0.5f, 0.5f);
            tv.y = fmaf(rv.y, 0.5f, 0.5f);
            tv.z = fmaf(rv.z, 0.5f, 0.5f);
            tv.w = fmaf(rv.w, 0.5f, 0.5f);
        }
        reinterpret_cast<float4*>(inT)[r * 6 + q] = iv;
        reinterpret_cast<float4*>(tgT)[r * 6 + q] = tv;
    }
    __syncthreads();   // A: halo ready

    // ---- step 2: w-direction sliding 9-sums, 96 threads = 24 rows x 4
    // quads. Thread (r,q) covers outputs wo=4q..4q+3, needing halo floats
    // 4q..4q+11 = three aligned float4s. 6 b128 reads, 5 b128 writes.
    if (tid < 96) {
        const int r = tid >> 2, q = tid & 3;
        const float4* i4 = reinterpret_cast<const float4*>(inT) + r * 6 + q;
        const float4* t4 = reinterpret_cast<const float4*>(tgT) + r * 6 + q;
        float4 ia = i4[0], ib = i4[1], ic = i4[2];
        float4 ta = t4[0], tb = t4[1], tc = t4[2];
        const float pi[12] = {ia.x, ia.y, ia.z, ia.w, ib.x, ib.y, ib.z, ib.w,
                              ic.x, ic.y, ic.z, ic.w};
        const float pt[12] = {ta.x, ta.y, ta.z, ta.w, tb.x, tb.y, tb.z, tb.w,
                              tc.x, tc.y, tc.z, tc.w};
        float4 o[5];   // o[f] = outputs j=0..3 of field f
        #pragma unroll
        for (int f = 0; f < 5; ++f) {
            float s = 0.f;
            float v[12];
            #pragma unroll
            for (int k = 0; k < 12; ++k) {
                const float t = pt[k], iv = pi[k];
                v[k] = (f == 0) ? t
                     : (f == 1) ? iv
                     : (f == 2) ? t * t
                     : (f == 3) ? iv * iv
                                : iv * t;
            }
            #pragma unroll
            for (int k = 0; k < 9; ++k) s += v[k];
            o[f].x = s;
            s += v[9]  - v[0]; o[f].y = s;
            s += v[10] - v[1]; o[f].z = s;
            s += v[11] - v[2]; o[f].w = s;
        }
        float4* w4 = reinterpret_cast<float4*>(tmp5) + r * 4 + q;
        #pragma unroll
        for (int f = 0; f < 5; ++f) w4[f * T5S4] = o[f];
    }
    __syncthreads();   // B: tmp5 ready

    // ---- step 3: h-direction sliding 9-sums, 80 threads = 5 fields x 16 w.
    // Read the 24-value column once into registers, slide in VGPRs.
    if (tid < 80) {
        const int f = tid >> 4, w = tid & 15;
        const float* bp = tmp5 + f * T5S + w;
        float col[24];
        #pragma unroll
        for (int j = 0; j < 24; ++j) col[j] = bp[j * 16];
        float s = 0.f;
        #pragma unroll
        for (int r = 0; r < 8; ++r) s += col[r];
        float* pb = Pbuf + f * PBS + w;
        #pragma unroll
        for (int ho = 0; ho < 16; ++ho) {
            s += col[ho + 8];
            pb[ho * 16] = s;
            s -= col[ho];
        }
    }
    __syncthreads();   // C: Pbuf ready
}

__global__ void __launch_bounds__(256)
cc3d_main(const float* __restrict__ in, const float* __restrict__ tg,
          const float* __restrict__ fl, float* __restrict__ out,
          double* __restrict__ acc_ws, unsigned* __restrict__ cnt_ws)
{
    __shared__ float inT[24 * 24];
    __shared__ float tgT[24 * 24];
    __shared__ float tmp5[5 * T5S];
    __shared__ float Pbuf[5 * PBS];
    __shared__ float red[4];

    const int tid = threadIdx.x;
    const int w0 = blockIdx.x * TW;
    const int h0 = blockIdx.y * TH;
    const int bz = blockIdx.z;
    const int b  = bz / NDCH;
    const int d0 = (bz - b * NDCH) * DCHUNK;

    // D-direction ring of 9 plane values per field, statically indexed.
    float ring[45];
    #pragma unroll
    for (int i = 0; i < 45; ++i) ring[i] = 0.f;
    float S[5] = {0.f, 0.f, 0.f, 0.f, 0.f};
    float acc = 0.f;

    // ---- prefill planes d0-4 .. d0+3 into ring slots 0..7 ----
    #pragma unroll
    for (int l = 0; l < 8; ++l) {
        int dp = d0 - 4 + l;          // upper bound can't fail in prefill
        bool valid = (dp >= 0);       // block-uniform
        if (valid) compute_plane(in, tg, b, dp, h0, w0, tid, inT, tgT, tmp5, Pbuf);
        #pragma unroll
        for (int f = 0; f < 5; ++f) {
            float pv = valid ? Pbuf[f * PBS + tid] : 0.f;
            ring[f * 9 + l] = pv;
            S[f] += pv;
        }
    }

    // ---- main march over outputs d0 .. d0+DCHUNK-1 ----
    for (int jbase = 0; jbase < DCHUNK; jbase += 9) {
        #pragma unroll
        for (int jj = 0; jj < 9; ++jj) {
            int j = jbase + jj;
            if (j < DCHUNK) {         // block-uniform guard
                int dout = d0 + j;
                int dp = dout + 4;
                bool valid = (dp < ND);  // block-uniform
                if (valid) compute_plane(in, tg, b, dp, h0, w0, tid, inT, tgT, tmp5, Pbuf);
                const int slot = (jj + 8) % 9;   // compile-time (jbase % 9 == 0)
                #pragma unroll
                for (int f = 0; f < 5; ++f) {
                    float pn = valid ? Pbuf[f * PBS + tid] : 0.f;
                    S[f] += pn - ring[f * 9 + slot];
                    ring[f * 9 + slot] = pn;
                }
                int hh = tid >> 4, ww = tid & 15;
                long fidx = ((long)((b * ND + dout) * NH + (h0 + hh))) * NW + (w0 + ww);
                float x = fl[fidx];
                float wgt = 1.0f / (1.0f + __expf(-x));   // sigmoid, GAMMA=1
                float Ts = S[0], Is = S[1], TTs = S[2], IIs = S[3], ITs = S[4];
                float Ihat = Is * INV_K;
                float That = Ts * INV_K;
                float cross = ITs - Ihat * Ts - That * Is + That * Ihat * 729.0f;
                float T_var = TTs - 2.0f * That * Ts + That * That * 729.0f;
                float I_var = IIs - 2.0f * Ihat * Is + Ihat * Ihat * 729.0f;
                float cc = cross * cross * wgt / (T_var * I_var + 1e-5f);
                acc += cc;
            }
        }
    }

    // ---- block reduction -> device atomic; last block finalizes ----
    #pragma unroll
    for (int off = 32; off > 0; off >>= 1) acc += __shfl_down(acc, off);
    if ((tid & 63) == 0) red[tid >> 6] = acc;
    __syncthreads();
    if (tid == 0) {
        const double v = (double)red[0] + (double)red[1] + (double)red[2] + (double)red[3];
        atomicAdd(acc_ws, v);
        __threadfence();
        const unsigned done = atomicAdd(cnt_ws, 1u);
        if (done == (unsigned)(NBLOCKS - 1)) {
            __threadfence();
            const double a = atomicAdd(acc_ws, 0.0);   // coherent read
            out[0] = (float)(-(a * INV_COUNT));
        }
    }
}

extern "C" void kernel_launch(void* const* d_in, const int* in_sizes, int n_in,
                              void* d_out, int out_size, void* d_ws, size_t ws_size,
                              hipStream_t stream)
{
    const float* in = (const float*)d_in[0];   // 'input'
    const float* tg = (const float*)d_in[1];   // 'target'
    const float* fl = (const float*)d_in[2];   // 'flow'
    float* out = (float*)d_out;
    double* acc = (double*)d_ws;
    unsigned* cnt = (unsigned*)((char*)d_ws + 8);

    hipMemsetAsync(d_ws, 0, 16, stream);  // zero acc + counter (graph-safe)

    dim3 grid(NW / TW, NH / TH, NB * NDCH);  // (10, 10, 10) = 1000 blocks
    cc3d_main<<<grid, dim3(256), 0, stream>>>(in, tg, fl, out, acc, cnt);
}

// Round 7
// 199.808 us; speedup vs baseline: 1.2776x; 1.1996x over previous
//
#include <hip/hip_runtime.h>

// crossCorrelation3D: local (9x9x9) NCC loss, fused single kernel.
// B=2, C=1, D=H=W=160, fp32. Output = -mean(cc), scalar.
//
// R7 model (fits R2..R6): the per-CU LDS pipe is the throughput ceiling
// (R2: ~1640 cyc/plane of DS work vs 1830 measured); R6 cut DS work but
// starved the pipe (96/80-lane phases between barriers -> pipe idle);
// grids >1024 blocks add a dispatch tail at ~4 blocks/CU residency.
// R7: grid 1000 (all-concurrent), 2-stage SW pipeline so the pipe stays
// fed while DS work drops ~2x:
//  phaseX: waves0-2 (192 ln) step2(plane i): w-pair sliding, float2 LDS
//          (10 b64 rd + 5 b64 wr/lane);  wave3 (40 ln) step3(plane i-1):
//          float2 column reads + 9-deep register ring -> Pbuf.
//          (tmp5 double-buffered so both run concurrently.)
//  B1
//  phaseY: store prefetched halo(i+1) (dbuf), issue loads(i+2), flow
//          prefetch, ring ingest(plane i-1) + formula(output i-9).
//  B2
// 2 barriers/plane (was 3). Invalid boundary planes run on zeroed halos
// (uniform control flow; loads skipped). __launch_bounds__(256,4) pins
// VGPR <= 128 so 4 blocks/CU residency survives (grid 1000 needs 3.9).

constexpr int NB = 2, ND = 160, NH = 160, NW = 160;
constexpr int TH = 16, TW = 16;
constexpr int DCHUNK = 32;
constexpr int NDCH = ND / DCHUNK;          // 5
constexpr int NBLOCKS = (NW / TW) * (NH / TH) * NB * NDCH;  // 1000
constexpr int NP = DCHUNK + 8;             // 40 planes/block, dp = d0-4+p
constexpr float INV_K = 1.0f / 729.0f;
constexpr double INV_COUNT = 1.0 / (double(NB) * ND * NH * NW);
constexpr long PLSTRIDE = (long)NH * NW;   // 25600
constexpr int T5S = 392;                   // tmp5 field stride (even, b64 ok)
constexpr int PBS = 264;                   // Pbuf field stride

__global__ void __launch_bounds__(256, 4)
cc3d_main(const float* __restrict__ in, const float* __restrict__ tg,
          const float* __restrict__ fl, float* __restrict__ out,
          double* __restrict__ acc_ws, unsigned* __restrict__ cnt_ws)
{
    __shared__ float inH[2][24 * 24];
    __shared__ float tgH[2][24 * 24];
    __shared__ float tmp5[2][5 * T5S];
    __shared__ float Pbuf[5 * PBS];
    __shared__ float red[4];

    const int tid = threadIdx.x;
    const int w0 = blockIdx.x * TW;
    const int h0 = blockIdx.y * TH;
    const int bz = blockIdx.z;
    const int b  = bz / NDCH;
    const int d0 = (bz - b * NDCH) * DCHUNK;

    // ---- halo-load lane mapping (tid<144: row hr, 4-wide segment hq) ----
    const int hr = tid / 6, hq = tid - hr * 6;
    const int gh = h0 - 4 + hr;
    const int gw = w0 - 4 + hq * 4;     // 4-seg entirely in or out of bounds
    const bool ld_ok = (tid < 144) &&
        ((unsigned)gh < (unsigned)NH) && ((unsigned)gw < (unsigned)NW);
    const long haloBase = (long)b * ND * PLSTRIDE + (long)gh * NW + gw;

    const int hh = tid >> 4, ww = tid & 15;
    const long flBase = (long)b * ND * PLSTRIDE + (long)(h0 + hh) * NW + (w0 + ww);

    float4 pvi, pvt;                    // in-flight halo loads

    auto issue = [&](int p) {           // global loads for plane p
        const int dp = d0 - 4 + p;
        if (p < NP && ld_ok && dp >= 0 && dp < ND) {
            const float* pi = in + haloBase + (long)dp * PLSTRIDE;
            const float* pt = tg + haloBase + (long)dp * PLSTRIDE;
            pvi = *reinterpret_cast<const float4*>(pi);
            pvt = *reinterpret_cast<const float4*>(pt);
        }
    };
    auto store_halo = [&](int p) {      // prefetched regs -> halo dbuf p&1
        if (p >= NP) return;            // block-uniform
        const int dp = d0 - 4 + p;
        const bool v = (dp >= 0) && (dp < ND);
        if (tid < 144) {
            float4 wi = make_float4(0.f, 0.f, 0.f, 0.f);
            float4 wt = make_float4(0.f, 0.f, 0.f, 0.f);
            if (v && ld_ok) {
                wi = pvi;
                wt.x = fmaf(pvt.x, 0.5f, 0.5f);   // t=(raw+1)/2 at store so
                wt.y = fmaf(pvt.y, 0.5f, 0.5f);   // zero-pad stays t=0
                wt.z = fmaf(pvt.z, 0.5f, 0.5f);
                wt.w = fmaf(pvt.w, 0.5f, 0.5f);
            }
            reinterpret_cast<float4*>(inH[p & 1])[tid] = wi;
            reinterpret_cast<float4*>(tgH[p & 1])[tid] = wt;
        }
    };
    auto step2 = [&](int p) {           // waves 0-2: w-pair sliding 9-sums
        const int r = tid >> 3, wp = tid & 7, w = wp * 2;
        const float2* i2 = reinterpret_cast<const float2*>(&inH[p & 1][r * 24 + w]);
        const float2* t2 = reinterpret_cast<const float2*>(&tgH[p & 1][r * 24 + w]);
        float2 a0 = i2[0], a1 = i2[1], a2 = i2[2], a3 = i2[3], a4 = i2[4];
        float2 b0 = t2[0], b1 = t2[1], b2 = t2[2], b3 = t2[3], b4 = t2[4];
        const float iv[10] = {a0.x, a0.y, a1.x, a1.y, a2.x, a2.y, a3.x, a3.y, a4.x, a4.y};
        const float tv[10] = {b0.x, b0.y, b1.x, b1.y, b2.x, b2.y, b3.x, b3.y, b4.x, b4.y};
        float s0 = 0.f, s1 = 0.f, s2 = 0.f, s3 = 0.f, s4 = 0.f;
        #pragma unroll
        for (int k = 0; k < 9; ++k) {
            const float i_ = iv[k], t_ = tv[k];
            s0 += t_;
            s1 += i_;
            s2 = fmaf(t_, t_, s2);
            s3 = fmaf(i_, i_, s3);
            s4 = fmaf(i_, t_, s4);
        }
        float2 o0, o1, o2, o3, o4;
        o0.x = s0; o0.y = s0 + tv[9] - tv[0];
        o1.x = s1; o1.y = s1 + iv[9] - iv[0];
        o2.x = s2; o2.y = s2 + tv[9] * tv[9] - tv[0] * tv[0];
        o3.x = s3; o3.y = s3 + iv[9] * iv[9] - iv[0] * iv[0];
        o4.x = s4; o4.y = s4 + iv[9] * tv[9] - iv[0] * tv[0];
        float* base = &tmp5[p & 1][r * 16 + w];
        *reinterpret_cast<float2*>(base + 0 * T5S) = o0;
        *reinterpret_cast<float2*>(base + 1 * T5S) = o1;
        *reinterpret_cast<float2*>(base + 2 * T5S) = o2;
        *reinterpret_cast<float2*>(base + 3 * T5S) = o3;
        *reinterpret_cast<float2*>(base + 4 * T5S) = o4;
    };
    auto step3 = [&](int pm) {          // wave 3 lanes 0-39: h sliding 9-sums
        const int sid = tid - 192;
        if (sid < 40) {
            const int f = sid >> 3, wp = sid & 7, w = wp * 2;
            const float* bp = &tmp5[pm & 1][f * T5S + w];
            float2 rc[9];
            float2 s = make_float2(0.f, 0.f);
            #pragma unroll
            for (int r = 0; r < 8; ++r) {
                const float2 c = *reinterpret_cast<const float2*>(bp + r * 16);
                rc[r] = c;
                s.x += c.x; s.y += c.y;
            }
            float* pb = &Pbuf[f * PBS + w];
            #pragma unroll
            for (int ho = 0; ho < 16; ++ho) {
                const float2 c = *reinterpret_cast<const float2*>(bp + (ho + 8) * 16);
                rc[(ho + 8) % 9] = c;            // compile-time slot
                s.x += c.x; s.y += c.y;
                *reinterpret_cast<float2*>(pb + ho * 16) = s;
                const float2 o = rc[ho % 9];     // compile-time slot
                s.x -= o.x; s.y -= o.y;
            }
        }
    };

    float ring[45];
    #pragma unroll
    for (int i = 0; i < 45; ++i) ring[i] = 0.f;
    float S[5] = {0.f, 0.f, 0.f, 0.f, 0.f};
    float acc = 0.f;
    float flw_next = 0.f;

    // ---- prologue: halo(0) stored, loads(1) in flight ----
    issue(0);
    store_halo(0);
    issue(1);
    __syncthreads();

    // ---- iteration i = 0 (no step3/ingest/formula yet) ----
    if (tid < 192) step2(0);
    __syncthreads();                    // B1
    store_halo(1);
    issue(2);
    __syncthreads();                    // B2

    // ---- iterations i = 1..40; ring slot = (i-1)%9 = jj (static) ----
    for (int pbase = 1; pbase <= 37; pbase += 9) {
        #pragma unroll
        for (int jj = 0; jj < 9; ++jj) {
            const int i = pbase + jj;
            if (i <= 40) {              // block-uniform
                // ---- phase X ----
                if (tid < 192) {
                    if (i <= 39) step2(i);
                } else {
                    step3(i - 1);
                }
                __syncthreads();        // B1: tmp5(i) + Pbuf(i-1) ready

                // ---- phase Y ----
                const float flw_cur = flw_next;
                if (i >= 8 && i <= 39)
                    flw_next = fl[flBase + (long)(d0 + i - 8) * PLSTRIDE];
                store_halo(i + 1);      // uses loads issued at iter i-1
                issue(i + 2);

                #pragma unroll
                for (int f = 0; f < 5; ++f) {
                    const float pn = Pbuf[f * PBS + tid];
                    S[f] += pn - ring[jj * 5 + f];
                    ring[jj * 5 + f] = pn;
                }
                if (i >= 9) {           // output j = i-9
                    const float wgt = 1.0f / (1.0f + __expf(-flw_cur));
                    const float Ts = S[0], Is = S[1], TTs = S[2], IIs = S[3], ITs = S[4];
                    const float Ihat = Is * INV_K;
                    const float That = Ts * INV_K;
                    const float cross = ITs - Ihat * Ts - That * Is + That * Ihat * 729.0f;
                    const float T_var = TTs - 2.0f * That * Ts + That * That * 729.0f;
                    const float I_var = IIs - 2.0f * Ihat * Is + Ihat * Ihat * 729.0f;
                    acc += cross * cross * wgt / (T_var * I_var + 1e-5f);
                }
                __syncthreads();        // B2
            }
        }
    }

    // ---- block reduction -> device atomic; last block finalizes ----
    #pragma unroll
    for (int off = 32; off > 0; off >>= 1) acc += __shfl_down(acc, off);
    if ((tid & 63) == 0) red[tid >> 6] = acc;
    __syncthreads();
    if (tid == 0) {
        const double v = (double)red[0] + (double)red[1] + (double)red[2] + (double)red[3];
        atomicAdd(acc_ws, v);
        __threadfence();
        const unsigned done = atomicAdd(cnt_ws, 1u);
        if (done == (unsigned)(NBLOCKS - 1)) {
            __threadfence();
            const double a = atomicAdd(acc_ws, 0.0);   // coherent read
            out[0] = (float)(-(a * INV_COUNT));
        }
    }
}

extern "C" void kernel_launch(void* const* d_in, const int* in_sizes, int n_in,
                              void* d_out, int out_size, void* d_ws, size_t ws_size,
                              hipStream_t stream)
{
    const float* in = (const float*)d_in[0];   // 'input'
    const float* tg = (const float*)d_in[1];   // 'target'
    const float* fl = (const float*)d_in[2];   // 'flow'
    float* out = (float*)d_out;
    double* acc = (double*)d_ws;
    unsigned* cnt = (unsigned*)((char*)d_ws + 8);

    hipMemsetAsync(d_ws, 0, 16, stream);  // zero acc + counter (graph-safe)

    dim3 grid(NW / TW, NH / TH, NB * NDCH);  // (10, 10, 10) = 1000 blocks
    cc3d_main<<<grid, dim3(256), 0, stream>>>(in, tg, fl, out, acc, cnt);
}